// Round 2
// baseline (295.652 us; speedup 1.0000x reference)
//
#include <hip/hip_runtime.h>
#include <hip/hip_bf16.h>
#include <cstddef>
#include <cstdint>

// ---------------- problem constants ----------------
#define M_TOK   16384      // 32*512 tokens
#define N_CODE  8192       // NUM_LATENTS
#define K_DIM   256        // LATENT_DIM
#define NSPLIT  4
#define BM      128
#define BN      256        // R7: wider N-tile, 8-wave block, per-wave 64x64 unchanged
#define BK      32
#define KSTEPS  (K_DIM / BK)                 // 8
#define TILES   ((N_CODE / NSPLIT) / BN)     // 8
#define TOTAL_STEPS (TILES * KSTEPS)         // 64
// step buffer layout (48 KB): [xh 8K][xl 8K][wh 16K][wl 16K]
#define STEP_BYTES 49152
#define XH_OFF 0
#define XL_OFF 8192
#define WH_OFF 16384
#define WL_OFF 32768

typedef short bf16x8 __attribute__((ext_vector_type(8)));  // 8 bf16 = 4 VGPRs
typedef float f32x4  __attribute__((ext_vector_type(4)));

__device__ __forceinline__ unsigned short f2bf_rne(float f) {
    unsigned u = __float_as_uint(f);
    unsigned r = u + 0x7FFFu + ((u >> 16) & 1u);
    return (unsigned short)(r >> 16);
}
__device__ __forceinline__ float bf2f(unsigned short h) {
    union { unsigned u; float f; } c; c.u = ((unsigned)h) << 16; return c.f;
}

__device__ __forceinline__ void gload16(const void* g, void* l) {
    __builtin_amdgcn_global_load_lds(
        (const __attribute__((address_space(1))) void*)g,
        (__attribute__((address_space(3))) void*)l, 16, 0, 0);
}

// ---------------- prep: bf16 hi/lo split + fp32 norms ----------------
__global__ void vq_prep(const float* __restrict__ x, const float* __restrict__ cb,
                        unsigned short* __restrict__ xh, unsigned short* __restrict__ xl,
                        unsigned short* __restrict__ wh, unsigned short* __restrict__ wl,
                        float* __restrict__ x2, float* __restrict__ w2) {
    int gt   = blockIdx.x * blockDim.x + threadIdx.x;
    int row  = gt >> 6;
    int lane = gt & 63;
    if (row >= M_TOK + N_CODE) return;
    const float* src; unsigned short *dh, *dl; float* dn;
    if (row < M_TOK) {
        src = x + (size_t)row * K_DIM;
        dh = xh + (size_t)row * K_DIM; dl = xl + (size_t)row * K_DIM; dn = x2 + row;
    } else {
        int r = row - M_TOK;
        src = cb + (size_t)r * K_DIM;
        dh = wh + (size_t)r * K_DIM; dl = wl + (size_t)r * K_DIM; dn = w2 + r;
    }
    float4 v = ((const float4*)src)[lane];
    unsigned short h0 = f2bf_rne(v.x), h1 = f2bf_rne(v.y);
    unsigned short h2 = f2bf_rne(v.z), h3 = f2bf_rne(v.w);
    unsigned short l0 = f2bf_rne(v.x - bf2f(h0)), l1 = f2bf_rne(v.y - bf2f(h1));
    unsigned short l2 = f2bf_rne(v.z - bf2f(h2)), l3 = f2bf_rne(v.w - bf2f(h3));
    ushort4 hv; hv.x = h0; hv.y = h1; hv.z = h2; hv.w = h3;
    ushort4 lv; lv.x = l0; lv.y = l1; lv.z = l2; lv.w = l3;
    ((ushort4*)dh)[lane] = hv;
    ((ushort4*)dl)[lane] = lv;
    float s = v.x*v.x + v.y*v.y + v.z*v.z + v.w*v.w;
    #pragma unroll
    for (int off = 32; off > 0; off >>= 1) s += __shfl_down(s, off);
    if (lane == 0) *dn = s;
}

// ---------------- main: depth-3 counted-vmcnt pipelined 3-term MFMA GEMM + argmin ----------------
// R7 (T3+T4, m201-style two-barrier phase): __syncthreads() drains vmcnt(0) and thereby
// killed R6's prefetch. Here the per-step sequence is
//   s_waitcnt vmcnt(12)    <- wait ONLY this step's 6 stage loads; 12 newer stay in flight
//   s_barrier              <- all waves' step data present in LDS
//   ds_read 16x b128 ; s_waitcnt lgkmcnt(0)
//   s_barrier              <- all waves done reading this buffer
//   STAGE(step+3) into it  <- loads fly under the MFMA cluster (depth-3 ~ 5.6K cyc >> 900)
//   setprio(1); 48 MFMA; setprio(0)
// 8 waves (512 thr), BM=128 x BN=256, per-wave 64x64 (wave grid 2 rows x 4 cols).
// LDS = 3 x 48 KB + reduce arrays -> 1 block/CU, 2 waves/SIMD (same as before).
// Swizzle relation identical to R6 (verified conflict-free, SQ_LDS_BANK_CONFLICT=0):
// LDS slot s at row r holds global chunk s ^ ((r>>1)&3); read slot quad ^ ((l15>>1)&3).
// Accumulation: same ascending K=32 slices, same MFMA triple -> bit-exact scores.
__global__ __launch_bounds__(512, 2)
void vq_main_mfma(const unsigned short* __restrict__ xh, const unsigned short* __restrict__ xl,
                  const unsigned short* __restrict__ wh, const unsigned short* __restrict__ wl,
                  const float* __restrict__ x2, const float* __restrict__ w2,
                  float* __restrict__ pminv, int* __restrict__ pmini) {
    __shared__ __align__(1024) char sb[3][STEP_BYTES];   // 144 KB
    __shared__ float red_d[BM][4];
    __shared__ int   red_i[BM][4];

    // XCD-aware remap: split = xcd&3 keeps one 2 MB codebook slice L2-resident per XCD
    const int fid   = blockIdx.y * NSPLIT + blockIdx.x;
    const int xcd   = fid & 7;
    const int split = xcd & 3;
    const int mtile = ((xcd >> 2) << 6) + (fid >> 3);
    const int gm    = mtile * BM;

    const int tid   = threadIdx.x;
    const int w     = tid >> 6;              // wave 0..7
    const int lane  = tid & 63;
    const int wr    = w >> 2;                // row half (0/1)
    const int wc    = w & 3;                 // col quarter (0..3)
    const int quad  = lane >> 4;             // 0..3
    const int l15   = lane & 15;

    // staging constants: per step each thread issues 6 gload16
    const int srow4 = lane >> 2;                       // 0..15
    const int sg    = (lane & 3) ^ ((lane >> 3) & 3);  // pre-swizzled global chunk

    const char* xhp = (const char*)xh;
    const char* xlp = (const char*)xl;
    const char* whp = (const char*)wh;
    const char* wlp = (const char*)wl;

    // x rows: wave w covers [w*16, w*16+16); w rows: [w*32, w*32+32) in 2 rounds of 16
    const size_t xg0 = (size_t)(gm + w*16 + srow4) * (K_DIM*2) + (size_t)sg*16;
    const size_t wg0 = (size_t)(w*32 + srow4) * (K_DIM*2) + (size_t)sg*16;
    const size_t wg1 = wg0 + (size_t)16 * (K_DIM*2);
    const unsigned lx = (unsigned)w*1024 + (unsigned)lane*16;   // LDS dest, x region
    const unsigned lw = (unsigned)w*2048 + (unsigned)lane*16;   // LDS dest, w region

    // per-lane row constants (issued FIRST so they are oldest in the vmcnt queue)
    float x2r[16];
    #pragma unroll
    for (int rt = 0; rt < 4; ++rt)
        #pragma unroll
        for (int reg = 0; reg < 4; ++reg)
            x2r[rt*4+reg] = x2[gm + wr*64 + rt*16 + quad*4 + reg];

    float minv[16];
    int   mini[16];
    #pragma unroll
    for (int i = 0; i < 16; ++i) { minv[i] = 3.4e38f; mini[i] = 0; }

    auto stage = [&](int s, char* buf) {
        const size_t kb  = (size_t)(s & (KSTEPS-1)) * (BK*2);
        const size_t nbo = ((size_t)(split*(N_CODE/NSPLIT) + (s >> 3) * BN)) * (K_DIM*2);
        gload16(xhp + xg0 + kb,        buf + XH_OFF + lx);
        gload16(xlp + xg0 + kb,        buf + XL_OFF + lx);
        gload16(whp + nbo + wg0 + kb,  buf + WH_OFF + lw);
        gload16(whp + nbo + wg1 + kb,  buf + WH_OFF + lw + 1024);
        gload16(wlp + nbo + wg0 + kb,  buf + WL_OFF + lw);
        gload16(wlp + nbo + wg1 + kb,  buf + WL_OFF + lw + 1024);
    };

    char* bufA = &sb[0][0];
    char* bufB = &sb[1][0];
    char* bufC = &sb[2][0];
    stage(0, bufA); stage(1, bufB); stage(2, bufC);   // depth-3 prologue

    const int slb = (quad ^ ((l15 >> 1) & 3)) * 16;   // swizzled slot byte offset

    for (int tile = 0; tile < TILES; ++tile) {
        f32x4 acc[4][4];
        #pragma unroll
        for (int rt = 0; rt < 4; ++rt)
            #pragma unroll
            for (int ct = 0; ct < 4; ++ct)
                acc[rt][ct] = (f32x4){0.f, 0.f, 0.f, 0.f};

        for (int kcs = 0; kcs < KSTEPS; ++kcs) {
            const int step = tile * KSTEPS + kcs;

            // counted wait: retire this step's 6 stage loads; keep 12 newer in flight
            if (step < TOTAL_STEPS - 2)       asm volatile("s_waitcnt vmcnt(12)" ::: "memory");
            else if (step == TOTAL_STEPS - 2) asm volatile("s_waitcnt vmcnt(6)" ::: "memory");
            else                              asm volatile("s_waitcnt vmcnt(0)" ::: "memory");
            __builtin_amdgcn_s_barrier();                 // barrier A: data present
            __builtin_amdgcn_sched_barrier(0);            // no reads hoist above A

            bf16x8 ah[4], al[4], bh[4], bl[4];
            #pragma unroll
            for (int rt = 0; rt < 4; ++rt) {
                const int off = (wr*64 + rt*16 + l15) * (BK*2) + slb;
                ah[rt] = *(const bf16x8*)(bufA + XH_OFF + off);
                al[rt] = *(const bf16x8*)(bufA + XL_OFF + off);
            }
            #pragma unroll
            for (int ct = 0; ct < 4; ++ct) {
                const int off = (wc*64 + ct*16 + l15) * (BK*2) + slb;
                bh[ct] = *(const bf16x8*)(bufA + WH_OFF + off);
                bl[ct] = *(const bf16x8*)(bufA + WL_OFF + off);
            }
            asm volatile("s_waitcnt lgkmcnt(0)" ::: "memory");  // reads landed in VGPRs
            __builtin_amdgcn_sched_barrier(0);
            __builtin_amdgcn_s_barrier();                 // barrier B: buffer free
            __builtin_amdgcn_sched_barrier(0);            // no stage hoists above B

            const int sn = step + 3;
            if (sn < TOTAL_STEPS) stage(sn, bufA);        // refill just-freed buffer

            __builtin_amdgcn_s_setprio(1);
            #pragma unroll
            for (int rt = 0; rt < 4; ++rt)
                #pragma unroll
                for (int ct = 0; ct < 4; ++ct) {
                    acc[rt][ct] = __builtin_amdgcn_mfma_f32_16x16x32_bf16(al[rt], bh[ct], acc[rt][ct], 0, 0, 0);
                    acc[rt][ct] = __builtin_amdgcn_mfma_f32_16x16x32_bf16(ah[rt], bl[ct], acc[rt][ct], 0, 0, 0);
                    acc[rt][ct] = __builtin_amdgcn_mfma_f32_16x16x32_bf16(ah[rt], bh[ct], acc[rt][ct], 0, 0, 0);
                }
            __builtin_amdgcn_s_setprio(0);

            char* t = bufA; bufA = bufB; bufB = bufC; bufC = t;   // rotate
        }

        // score tile: dist = (x2 - 2*xw) + w2, C layout col=lane&15, row=quad*4+reg
        const int nb = split * (N_CODE / NSPLIT) + tile * BN;
        float w2c[4];
        int   cidx[4];
        #pragma unroll
        for (int ct = 0; ct < 4; ++ct) {
            cidx[ct] = nb + wc*64 + ct*16 + l15;
            w2c[ct]  = w2[cidx[ct]];
        }
        #pragma unroll
        for (int rt = 0; rt < 4; ++rt)
            #pragma unroll
            for (int ct = 0; ct < 4; ++ct) {
                #pragma unroll
                for (int reg = 0; reg < 4; ++reg) {
                    float d = (x2r[rt*4+reg] - 2.0f * acc[rt][ct][reg]) + w2c[ct];
                    int r16 = rt*4 + reg;
                    if (d < minv[r16]) { minv[r16] = d; mini[r16] = cidx[ct]; }
                }
            }
    }

    // reduce across the 16 lanes (same rows, different cols); tie-break lower index
    #pragma unroll
    for (int r16 = 0; r16 < 16; ++r16) {
        float d  = minv[r16];
        int   ix = mini[r16];
        #pragma unroll
        for (int off = 1; off < 16; off <<= 1) {
            float od = __shfl_xor(d, off);
            int   oi = __shfl_xor(ix, off);
            if (od < d || (od == d && oi < ix)) { d = od; ix = oi; }
        }
        if (l15 == 0) {
            int row_local = wr*64 + (r16 >> 2)*16 + quad*4 + (r16 & 3);
            red_d[row_local][wc] = d;
            red_i[row_local][wc] = ix;
        }
    }
    __syncthreads();
    // combine the four col-quarters, write per-split partials
    if (tid < BM) {
        float d  = red_d[tid][0];
        int   ix = red_i[tid][0];
        #pragma unroll
        for (int j = 1; j < 4; ++j) {
            float dj = red_d[tid][j];
            int   ij = red_i[tid][j];
            if (dj < d || (dj == d && ij < ix)) { d = dj; ix = ij; }
        }
        pminv[(size_t)(gm + tid) * NSPLIT + split] = d;
        pmini[(size_t)(gm + tid) * NSPLIT + split] = ix;
    }
}

// ---------------- epilogue: reduce NSPLIT partials in-wave, then z_q/z/x/indices ----------------
__global__ void vq_gather(const float* __restrict__ x, const float* __restrict__ cb,
                          const float* __restrict__ pminv, const int* __restrict__ pmini,
                          float* __restrict__ out) {
    int t = blockIdx.x * blockDim.x + threadIdx.x;   // float4 units
    int m = t >> 6;
    int q = t & 63;        // == lane: one wave handles exactly one row

    // NSPLIT-way split reduce, replicated across lanes via xor shuffles
    float d  = pminv[(size_t)m * NSPLIT + (q & (NSPLIT-1))];
    int   ix = pmini[(size_t)m * NSPLIT + (q & (NSPLIT-1))];
    #pragma unroll
    for (int off = 1; off < NSPLIT; off <<= 1) {
        float od = __shfl_xor(d, off);
        int   oi = __shfl_xor(ix, off);
        if (od < d || (od == d && oi < ix)) { d = od; ix = oi; }
    }

    float4 xv = ((const float4*)x)[t];
    float4 zv = ((const float4*)cb)[(size_t)ix * 64 + q];
    float4 zq;
    zq.x = xv.x + (zv.x - xv.x);
    zq.y = xv.y + (zv.y - xv.y);
    zq.z = xv.z + (zv.z - xv.z);
    zq.w = xv.w + (zv.w - xv.w);
    float4* o = (float4*)out;
    const int ELEM4 = M_TOK * 64;
    o[t]           = zq;     // z_q
    o[t + ELEM4]   = zv;     // z
    o[t + 2*ELEM4] = xv;     // x
    if (q == 0) out[(size_t)3 * M_TOK * K_DIM + m] = (float)ix;
}

// ---------------- launcher ----------------
extern "C" void kernel_launch(void* const* d_in, const int* in_sizes, int n_in,
                              void* d_out, int out_size, void* d_ws, size_t ws_size,
                              hipStream_t stream) {
    const float* x  = (const float*)d_in[0];   // 16384 x 256
    const float* cb = (const float*)d_in[1];   // 8192 x 256
    float* out = (float*)d_out;

    // workspace layout
    char* p = (char*)d_ws;
    unsigned short* xh = (unsigned short*)p;  p += (size_t)M_TOK  * K_DIM * 2;  // 8 MB
    unsigned short* xl = (unsigned short*)p;  p += (size_t)M_TOK  * K_DIM * 2;  // 8 MB
    unsigned short* wh = (unsigned short*)p;  p += (size_t)N_CODE * K_DIM * 2;  // 4 MB
    unsigned short* wl = (unsigned short*)p;  p += (size_t)N_CODE * K_DIM * 2;  // 4 MB
    float* x2    = (float*)p;  p += (size_t)M_TOK * 4;
    float* w2    = (float*)p;  p += (size_t)N_CODE * 4;
    float* pminv = (float*)p;  p += (size_t)M_TOK * NSPLIT * 4;
    int*   pmini = (int*)p;    p += (size_t)M_TOK * NSPLIT * 4;

    // prep: one wave per row, 24576 rows
    {
        int waves = M_TOK + N_CODE;
        vq_prep<<<(waves * 64 + 255) / 256, 256, 0, stream>>>(x, cb, xh, xl, wh, wl, x2, w2);
    }
    // main fused MFMA GEMM + argmin (depth-3 counted-vmcnt pipeline, 512-thread blocks)
    {
        dim3 grid(NSPLIT, M_TOK / BM);   // 4 x 128 = 512 blocks, 1 block/CU, 2 rounds
        vq_main_mfma<<<grid, 512, 0, stream>>>(xh, xl, wh, wl, x2, w2, pminv, pmini);
    }
    // epilogue (split-reduce fused in)
    {
        int t = M_TOK * (K_DIM / 4);     // 1048576 float4 threads
        vq_gather<<<t / 256, 256, 0, stream>>>(x, cb, pminv, pmini, out);
    }
}